// Round 2
// baseline (2516.941 us; speedup 1.0000x reference)
//
#include <hip/hip_runtime.h>

// out[n, u*4+s] = sum_{e: dst[e]==n} x[src[e], u] * sh[e, s]
// N=100000, U=32, S=4, E=3200000.
//
// Pipeline: bucket edges by dst>>6 (64 nodes/bucket, NB=1563 buckets),
// permuting payloads (sh float4 + packed src|dst_local) into sequential
// per-bucket streams. Accum: one block per bucket, LDS f32 accumulation,
// coalesced output store. No global float atomics, no random 16B reads.

#define U_DIM 32
#define S_DIM 4
#define US 128
#define LOG_NPB 6
#define NPB 64            // nodes per bucket
#define MAXNB 2048
#define PACK_SHIFT 20
#define PACK_MASK ((1 << PACK_SHIFT) - 1)
#define CHUNK 16          // edges per thread in hist/scatter

__global__ void __launch_bounds__(256) hist_kernel(
        const int* __restrict__ dst, int* __restrict__ counts, int E, int NB) {
    __shared__ int h[MAXNB];
    for (int b = threadIdx.x; b < NB; b += blockDim.x) h[b] = 0;
    __syncthreads();
    int base = blockIdx.x * (blockDim.x * CHUNK);
    for (int j = 0; j < CHUNK; ++j) {
        int e = base + j * blockDim.x + threadIdx.x;
        if (e < E) atomicAdd(&h[dst[e] >> LOG_NPB], 1);
    }
    __syncthreads();
    for (int b = threadIdx.x; b < NB; b += blockDim.x) {
        int c = h[b];
        if (c) atomicAdd(&counts[b], c);
    }
}

__global__ void __launch_bounds__(1024) scan_kernel(
        const int* __restrict__ counts, int* __restrict__ offsets,
        int* __restrict__ cursors, int NB, int E) {
    __shared__ int part[1024];
    int items = (NB + 1023) >> 10;
    int beg = threadIdx.x * items;
    int sum = 0;
    for (int j = 0; j < items; ++j) {
        int i = beg + j;
        if (i < NB) sum += counts[i];
    }
    part[threadIdx.x] = sum;
    __syncthreads();
    for (int off = 1; off < 1024; off <<= 1) {
        int v = (threadIdx.x >= off) ? part[threadIdx.x - off] : 0;
        __syncthreads();
        part[threadIdx.x] += v;
        __syncthreads();
    }
    int excl = part[threadIdx.x] - sum;
    for (int j = 0; j < items; ++j) {
        int i = beg + j;
        if (i < NB) {
            offsets[i] = excl;
            cursors[i] = excl;
            excl += counts[i];
        }
    }
    if (threadIdx.x == 0) offsets[NB] = E;
}

__global__ void __launch_bounds__(256) scatter_kernel(
        const int* __restrict__ dst, const int* __restrict__ src,
        const float4* __restrict__ sh, int* __restrict__ cursors,
        float4* __restrict__ psh, int* __restrict__ ppacked, int E, int NB) {
    __shared__ int cnt[MAXNB];
    for (int b = threadIdx.x; b < NB; b += blockDim.x) cnt[b] = 0;
    __syncthreads();
    int base = blockIdx.x * (blockDim.x * CHUNK);
    for (int j = 0; j < CHUNK; ++j) {
        int e = base + j * blockDim.x + threadIdx.x;
        if (e < E) atomicAdd(&cnt[dst[e] >> LOG_NPB], 1);
    }
    __syncthreads();
    for (int b = threadIdx.x; b < NB; b += blockDim.x) {
        int c = cnt[b];
        if (c) cnt[b] = atomicAdd(&cursors[b], c);   // bucket base for this block
    }
    __syncthreads();
    for (int j = 0; j < CHUNK; ++j) {
        int e = base + j * blockDim.x + threadIdx.x;
        if (e < E) {
            int d = dst[e];
            int b = d >> LOG_NPB;
            int pos = atomicAdd(&cnt[b], 1);
            psh[pos] = sh[e];                                    // coalesced read, dense bucket-stream write
            ppacked[pos] = src[e] | ((d & (NPB - 1)) << PACK_SHIFT);
        }
    }
}

// One block per bucket: 512 threads = 4 edge-lanes x 128 output elements.
__global__ void __launch_bounds__(512) accum_kernel(
        const float* __restrict__ x, const float* __restrict__ pshf,
        const int* __restrict__ ppacked, const int* __restrict__ offsets,
        float* __restrict__ out, int N) {
    __shared__ float acc[NPB * US];           // 32 KiB
    int b = blockIdx.x;
    int tid = threadIdx.x;
    for (int j = tid; j < NPB * US; j += 512) acc[j] = 0.f;
    __syncthreads();
    int tt = tid & 127;
    int lane = tid >> 7;                      // 0..3 (wave-pair aligned)
    int u = tt >> 2, s = tt & 3;
    int beg = offsets[b], end = offsets[b + 1];
    for (int i = beg + lane; i < end; i += 4) {
        int packed = ppacked[i];              // broadcast load
        float shv = pshf[i * 4 + s];          // one 16B broadcast per edge-lane
        int sv = packed & PACK_MASK;
        int dl = packed >> PACK_SHIFT;
        float v = x[sv * U_DIM + u] * shv;    // 128B row, 4-way broadcast
        atomicAdd(&acc[dl * US + tt], v);     // ds_add_f32, bank-conflict-free
    }
    __syncthreads();
    int nb_base = b << LOG_NPB;
    for (int j = tid; j < NPB * US; j += 512) {
        int node = nb_base + (j >> 7);
        if (node < N) out[(size_t)node * US + (j & 127)] = acc[j];
    }
}

// Fallback if workspace is too small: pure atomic scatter-add.
__global__ void __launch_bounds__(US) atomic_kernel(
        const float* __restrict__ x, const float* __restrict__ sh,
        const int* __restrict__ src, const int* __restrict__ dst,
        float* __restrict__ out, int E) {
    int e = blockIdx.x;
    int t = threadIdx.x;
    float v = x[src[e] * U_DIM + (t >> 2)] * sh[e * S_DIM + (t & 3)];
    atomicAdd(&out[(size_t)dst[e] * US + t], v);
}

extern "C" void kernel_launch(void* const* d_in, const int* in_sizes, int n_in,
                              void* d_out, int out_size, void* d_ws, size_t ws_size,
                              hipStream_t stream) {
    const float* x  = (const float*)d_in[0];
    const float* sh = (const float*)d_in[1];
    const int* src  = (const int*)d_in[2];
    const int* dst  = (const int*)d_in[3];
    float* out = (float*)d_out;

    const int E = in_sizes[2];
    const int N = in_sizes[0] / U_DIM;
    const int NB = (N + NPB - 1) >> LOG_NPB;

    // Workspace: psh float4[E] | ppacked int[E] | counts[NB] | offsets[NB+1] | cursors[NB]
    size_t need = (size_t)E * 16 + (size_t)E * 4 + (size_t)(3 * NB + 1) * 4;

    if (NB <= MAXNB && ws_size >= need) {
        float4* psh  = (float4*)d_ws;
        int* ppacked = (int*)(psh + E);
        int* counts  = ppacked + E;
        int* offsets = counts + NB;
        int* cursors = offsets + NB + 1;

        const int nchunk = (E + 256 * CHUNK - 1) / (256 * CHUNK);
        hipMemsetAsync(counts, 0, sizeof(int) * (size_t)NB, stream);
        hist_kernel<<<nchunk, 256, 0, stream>>>(dst, counts, E, NB);
        scan_kernel<<<1, 1024, 0, stream>>>(counts, offsets, cursors, NB, E);
        scatter_kernel<<<nchunk, 256, 0, stream>>>(dst, src, (const float4*)sh,
                                                   cursors, psh, ppacked, E, NB);
        accum_kernel<<<NB, 512, 0, stream>>>(x, (const float*)psh, ppacked,
                                             offsets, out, N);
    } else {
        hipMemsetAsync(out, 0, sizeof(float) * (size_t)out_size, stream);
        atomic_kernel<<<E, US, 0, stream>>>(x, sh, src, dst, out, E);
    }
}

// Round 3
// 804.201 us; speedup vs baseline: 3.1297x; 3.1297x over previous
//
#include <hip/hip_runtime.h>

// out[n, u*4+s] = sum_{e: dst[e]==n} x[src[e], u] * sh[e, s]
// N=100000, U=32, S=4, E=3200000.
//
// Full counting sort by dst with payload permutation (psh float4 + psrc int),
// then one 128-thread block per node accumulating in REGISTERS (no atomics in
// the hot loop — R2 showed LDS ds_add_f32 is a ~1 lane/cycle serial floor).

#define U_DIM 32
#define S_DIM 4
#define US 128

__global__ void __launch_bounds__(256) hist_kernel(
        const int* __restrict__ dst, int* __restrict__ counts, int E) {
    int e = blockIdx.x * blockDim.x + threadIdx.x;
    if (e < E) atomicAdd(&counts[dst[e]], 1);
}

// Single-block exclusive scan over N counts -> offsets[0..N], cursors[0..N-1].
__global__ void __launch_bounds__(1024) scan_kernel(
        const int* __restrict__ counts, int* __restrict__ offsets,
        int* __restrict__ cursors, int N, int E) {
    __shared__ int part[1024];
    int items = (N + 1023) >> 10;
    int beg = threadIdx.x * items;
    int sum = 0;
    for (int j = 0; j < items; ++j) {
        int i = beg + j;
        if (i < N) sum += counts[i];
    }
    part[threadIdx.x] = sum;
    __syncthreads();
    for (int off = 1; off < 1024; off <<= 1) {
        int v = (threadIdx.x >= off) ? part[threadIdx.x - off] : 0;
        __syncthreads();
        part[threadIdx.x] += v;
        __syncthreads();
    }
    int excl = part[threadIdx.x] - sum;
    for (int j = 0; j < items; ++j) {
        int i = beg + j;
        if (i < N) {
            offsets[i] = excl;
            cursors[i] = excl;
            excl += counts[i];
        }
    }
    if (threadIdx.x == 0) offsets[N] = E;
}

__global__ void __launch_bounds__(256) scatter_payload_kernel(
        const int* __restrict__ dst, const int* __restrict__ src,
        const float4* __restrict__ sh, int* __restrict__ cursors,
        float4* __restrict__ psh, int* __restrict__ psrc, int E) {
    int e = blockIdx.x * blockDim.x + threadIdx.x;
    if (e < E) {
        int pos = atomicAdd(&cursors[dst[e]], 1);
        psh[pos] = sh[e];
        psrc[pos] = src[e];
    }
}

// One block per node, 128 threads (2 waves), thread t owns (u = t>>2, s = t&3).
// psrc/psh reads are dense sequential (L1/L2), x gather is L2/L3-resident.
__global__ void __launch_bounds__(US) accum_payload_kernel(
        const float* __restrict__ x, const float* __restrict__ pshf,
        const int* __restrict__ psrc, const int* __restrict__ offsets,
        float* __restrict__ out) {
    int n = blockIdx.x;
    int t = threadIdx.x;
    int u = t >> 2, s = t & 3;
    int beg = offsets[n], end = offsets[n + 1];
    float acc0 = 0.f, acc1 = 0.f;
    int i = beg;
    for (; i + 1 < end; i += 2) {
        int s0 = psrc[i], s1 = psrc[i + 1];
        float h0 = pshf[i * 4 + s], h1 = pshf[(i + 1) * 4 + s];
        acc0 += x[s0 * U_DIM + u] * h0;
        acc1 += x[s1 * U_DIM + u] * h1;
    }
    if (i < end)
        acc0 += x[psrc[i] * U_DIM + u] * pshf[i * 4 + s];
    out[(size_t)n * US + t] = acc0 + acc1;
}

// --- Fallback tier 1: sorted edge-id list (R1 structure, ~845us proven) ---
__global__ void __launch_bounds__(256) scatter_ids_kernel(
        const int* __restrict__ dst, int* __restrict__ cursors,
        int* __restrict__ eids, int E) {
    int e = blockIdx.x * blockDim.x + threadIdx.x;
    if (e < E) {
        int pos = atomicAdd(&cursors[dst[e]], 1);
        eids[pos] = e;
    }
}

__global__ void __launch_bounds__(US) accum_ids_kernel(
        const float* __restrict__ x, const float* __restrict__ sh,
        const int* __restrict__ src, const int* __restrict__ offsets,
        const int* __restrict__ eids, float* __restrict__ out) {
    int n = blockIdx.x;
    int t = threadIdx.x;
    int u = t >> 2, s = t & 3;
    int beg = offsets[n], end = offsets[n + 1];
    float acc = 0.f;
    for (int i = beg; i < end; ++i) {
        int e = eids[i];
        acc += x[src[e] * U_DIM + u] * sh[e * S_DIM + (t & 3)];
    }
    out[(size_t)n * US + t] = acc;
}

// --- Fallback tier 2: pure global atomics ---
__global__ void __launch_bounds__(US) atomic_kernel(
        const float* __restrict__ x, const float* __restrict__ sh,
        const int* __restrict__ src, const int* __restrict__ dst,
        float* __restrict__ out, int E) {
    int e = blockIdx.x;
    int t = threadIdx.x;
    float v = x[src[e] * U_DIM + (t >> 2)] * sh[e * S_DIM + (t & 3)];
    atomicAdd(&out[(size_t)dst[e] * US + t], v);
}

extern "C" void kernel_launch(void* const* d_in, const int* in_sizes, int n_in,
                              void* d_out, int out_size, void* d_ws, size_t ws_size,
                              hipStream_t stream) {
    const float* x  = (const float*)d_in[0];
    const float* sh = (const float*)d_in[1];
    const int* src  = (const int*)d_in[2];
    const int* dst  = (const int*)d_in[3];
    float* out = (float*)d_out;

    const int E = in_sizes[2];
    const int N = in_sizes[0] / U_DIM;
    const int egrid = (E + 255) / 256;

    // Full path: psh float4[E] | psrc int[E] | counts[N] | offsets[N+1] | cursors[N]
    size_t need_full = (size_t)E * 16 + (size_t)E * 4 + (size_t)(3 * N + 1) * 4;
    // Ids path: eids int[E] | counts[N] | offsets[N+1] | cursors[N]
    size_t need_ids = (size_t)E * 4 + (size_t)(3 * N + 1) * 4;

    if (ws_size >= need_full) {
        float4* psh  = (float4*)d_ws;
        int* psrc    = (int*)(psh + E);
        int* counts  = psrc + E;
        int* offsets = counts + N;
        int* cursors = offsets + N + 1;

        hipMemsetAsync(counts, 0, sizeof(int) * (size_t)N, stream);
        hist_kernel<<<egrid, 256, 0, stream>>>(dst, counts, E);
        scan_kernel<<<1, 1024, 0, stream>>>(counts, offsets, cursors, N, E);
        scatter_payload_kernel<<<egrid, 256, 0, stream>>>(dst, src, (const float4*)sh,
                                                          cursors, psh, psrc, E);
        accum_payload_kernel<<<N, US, 0, stream>>>(x, (const float*)psh, psrc,
                                                   offsets, out);
    } else if (ws_size >= need_ids) {
        int* eids    = (int*)d_ws;
        int* counts  = eids + E;
        int* offsets = counts + N;
        int* cursors = offsets + N + 1;

        hipMemsetAsync(counts, 0, sizeof(int) * (size_t)N, stream);
        hist_kernel<<<egrid, 256, 0, stream>>>(dst, counts, E);
        scan_kernel<<<1, 1024, 0, stream>>>(counts, offsets, cursors, N, E);
        scatter_ids_kernel<<<egrid, 256, 0, stream>>>(dst, cursors, eids, E);
        accum_ids_kernel<<<N, US, 0, stream>>>(x, sh, src, offsets, eids, out);
    } else {
        hipMemsetAsync(out, 0, sizeof(float) * (size_t)out_size, stream);
        atomic_kernel<<<E, US, 0, stream>>>(x, sh, src, dst, out, E);
    }
}

// Round 4
// 563.440 us; speedup vs baseline: 4.4671x; 1.4273x over previous
//
#include <hip/hip_runtime.h>

// out[n, u*4+s] = sum_{e: dst[e]==n} x[src[e], u] * sh[e, s]
// N=100000, U=32, S=4, E=3200000.
//
// Counting sort by dst with payload permutation (psh float4 + psrc int), then
// one 128-thread block per node accumulating in REGISTERS (no atomics in the
// hot loop — R2: LDS ds_add_f32 is a ~1 lane/cycle serial floor).
// R3 lesson: 1-block scan over 100k = 260us serial wall; use 3-level scan.

#define U_DIM 32
#define S_DIM 4
#define US 128

constexpr int SCAN_BLOCK = 256;
constexpr int SCAN_ITEMS = 8;
constexpr int SCAN_CHUNK = SCAN_BLOCK * SCAN_ITEMS; // 2048

__global__ void __launch_bounds__(256) hist_kernel(
        const int* __restrict__ dst, int* __restrict__ counts, int E) {
    int e = blockIdx.x * blockDim.x + threadIdx.x;
    if (e < E) atomicAdd(&counts[dst[e]], 1);
}

__global__ void __launch_bounds__(SCAN_BLOCK) block_sum_kernel(
        const int* __restrict__ counts, int* __restrict__ bsums, int N) {
    __shared__ int sdata[SCAN_BLOCK];
    int base = blockIdx.x * SCAN_CHUNK;
    int sum = 0;
    for (int j = 0; j < SCAN_ITEMS; ++j) {
        int idx = base + j * SCAN_BLOCK + threadIdx.x;   // coalesced
        if (idx < N) sum += counts[idx];
    }
    sdata[threadIdx.x] = sum;
    __syncthreads();
    for (int off = SCAN_BLOCK / 2; off > 0; off >>= 1) {
        if (threadIdx.x < off) sdata[threadIdx.x] += sdata[threadIdx.x + off];
        __syncthreads();
    }
    if (threadIdx.x == 0) bsums[blockIdx.x] = sdata[0];
}

__global__ void scan_bsums_kernel(int* __restrict__ bsums, int nb) {
    if (threadIdx.x == 0 && blockIdx.x == 0) {
        int acc = 0;
        for (int i = 0; i < nb; ++i) { int v = bsums[i]; bsums[i] = acc; acc += v; }
    }
}

__global__ void __launch_bounds__(SCAN_BLOCK) scan_final_kernel(
        const int* __restrict__ counts, const int* __restrict__ bsums,
        int* __restrict__ offsets, int* __restrict__ cursors, int N, int E) {
    __shared__ int sdata[SCAN_BLOCK];
    int base = blockIdx.x * SCAN_CHUNK + threadIdx.x * SCAN_ITEMS;
    int local[SCAN_ITEMS];
    int tsum = 0;
    for (int j = 0; j < SCAN_ITEMS; ++j) {
        int idx = base + j;
        int v = (idx < N) ? counts[idx] : 0;
        local[j] = tsum;          // exclusive within thread
        tsum += v;
    }
    sdata[threadIdx.x] = tsum;
    __syncthreads();
    for (int off = 1; off < SCAN_BLOCK; off <<= 1) {
        int v = (threadIdx.x >= off) ? sdata[threadIdx.x - off] : 0;
        __syncthreads();
        sdata[threadIdx.x] += v;
        __syncthreads();
    }
    int excl = sdata[threadIdx.x] - tsum + bsums[blockIdx.x];
    for (int j = 0; j < SCAN_ITEMS; ++j) {
        int idx = base + j;
        if (idx < N) {
            int o = excl + local[j];
            offsets[idx] = o;
            cursors[idx] = o;
        }
    }
    if (blockIdx.x == 0 && threadIdx.x == 0) offsets[N] = E;
}

__global__ void __launch_bounds__(256) scatter_payload_kernel(
        const int* __restrict__ dst, const int* __restrict__ src,
        const float4* __restrict__ sh, int* __restrict__ cursors,
        float4* __restrict__ psh, int* __restrict__ psrc, int E) {
    int e = blockIdx.x * blockDim.x + threadIdx.x;
    if (e < E) {
        int pos = atomicAdd(&cursors[dst[e]], 1);
        psh[pos] = sh[e];
        psrc[pos] = src[e];
    }
}

// One block per node, 128 threads (2 waves), thread t owns (u = t>>2, s = t&3).
// psrc/psh reads are dense sequential (L1/L2), x gather is L2/L3-resident.
__global__ void __launch_bounds__(US) accum_payload_kernel(
        const float* __restrict__ x, const float* __restrict__ pshf,
        const int* __restrict__ psrc, const int* __restrict__ offsets,
        float* __restrict__ out) {
    int n = blockIdx.x;
    int t = threadIdx.x;
    int u = t >> 2, s = t & 3;
    int beg = offsets[n], end = offsets[n + 1];
    float acc0 = 0.f, acc1 = 0.f;
    int i = beg;
    for (; i + 1 < end; i += 2) {
        int s0 = psrc[i], s1 = psrc[i + 1];
        float h0 = pshf[i * 4 + s], h1 = pshf[(i + 1) * 4 + s];
        acc0 += x[s0 * U_DIM + u] * h0;
        acc1 += x[s1 * U_DIM + u] * h1;
    }
    if (i < end)
        acc0 += x[psrc[i] * U_DIM + u] * pshf[i * 4 + s];
    out[(size_t)n * US + t] = acc0 + acc1;
}

// --- Fallback tier 1: sorted edge-id list ---
__global__ void __launch_bounds__(256) scatter_ids_kernel(
        const int* __restrict__ dst, int* __restrict__ cursors,
        int* __restrict__ eids, int E) {
    int e = blockIdx.x * blockDim.x + threadIdx.x;
    if (e < E) {
        int pos = atomicAdd(&cursors[dst[e]], 1);
        eids[pos] = e;
    }
}

__global__ void __launch_bounds__(US) accum_ids_kernel(
        const float* __restrict__ x, const float* __restrict__ sh,
        const int* __restrict__ src, const int* __restrict__ offsets,
        const int* __restrict__ eids, float* __restrict__ out) {
    int n = blockIdx.x;
    int t = threadIdx.x;
    int u = t >> 2, s = t & 3;
    int beg = offsets[n], end = offsets[n + 1];
    float acc = 0.f;
    for (int i = beg; i < end; ++i) {
        int e = eids[i];
        acc += x[src[e] * U_DIM + u] * sh[e * S_DIM + s];
    }
    out[(size_t)n * US + t] = acc;
}

// --- Fallback tier 2: pure global atomics ---
__global__ void __launch_bounds__(US) atomic_kernel(
        const float* __restrict__ x, const float* __restrict__ sh,
        const int* __restrict__ src, const int* __restrict__ dst,
        float* __restrict__ out, int E) {
    int e = blockIdx.x;
    int t = threadIdx.x;
    float v = x[src[e] * U_DIM + (t >> 2)] * sh[e * S_DIM + (t & 3)];
    atomicAdd(&out[(size_t)dst[e] * US + t], v);
}

extern "C" void kernel_launch(void* const* d_in, const int* in_sizes, int n_in,
                              void* d_out, int out_size, void* d_ws, size_t ws_size,
                              hipStream_t stream) {
    const float* x  = (const float*)d_in[0];
    const float* sh = (const float*)d_in[1];
    const int* src  = (const int*)d_in[2];
    const int* dst  = (const int*)d_in[3];
    float* out = (float*)d_out;

    const int E = in_sizes[2];
    const int N = in_sizes[0] / U_DIM;
    const int egrid = (E + 255) / 256;
    const int nb = (N + SCAN_CHUNK - 1) / SCAN_CHUNK;

    // Full path: psh float4[E] | psrc int[E] | counts[N] | offsets[N+1] | cursors[N] | bsums[nb]
    size_t need_full = (size_t)E * 16 + (size_t)E * 4 + (size_t)(3 * N + 1 + nb) * 4;
    // Ids path: eids int[E] | counts[N] | offsets[N+1] | cursors[N] | bsums[nb]
    size_t need_ids = (size_t)E * 4 + (size_t)(3 * N + 1 + nb) * 4;

    if (ws_size >= need_full) {
        float4* psh  = (float4*)d_ws;
        int* psrc    = (int*)(psh + E);
        int* counts  = psrc + E;
        int* offsets = counts + N;
        int* cursors = offsets + N + 1;
        int* bsums   = cursors + N;

        hipMemsetAsync(counts, 0, sizeof(int) * (size_t)N, stream);
        hist_kernel<<<egrid, 256, 0, stream>>>(dst, counts, E);
        block_sum_kernel<<<nb, SCAN_BLOCK, 0, stream>>>(counts, bsums, N);
        scan_bsums_kernel<<<1, 64, 0, stream>>>(bsums, nb);
        scan_final_kernel<<<nb, SCAN_BLOCK, 0, stream>>>(counts, bsums, offsets, cursors, N, E);
        scatter_payload_kernel<<<egrid, 256, 0, stream>>>(dst, src, (const float4*)sh,
                                                          cursors, psh, psrc, E);
        accum_payload_kernel<<<N, US, 0, stream>>>(x, (const float*)psh, psrc,
                                                   offsets, out);
    } else if (ws_size >= need_ids) {
        int* eids    = (int*)d_ws;
        int* counts  = eids + E;
        int* offsets = counts + N;
        int* cursors = offsets + N + 1;
        int* bsums   = cursors + N;

        hipMemsetAsync(counts, 0, sizeof(int) * (size_t)N, stream);
        hist_kernel<<<egrid, 256, 0, stream>>>(dst, counts, E);
        block_sum_kernel<<<nb, SCAN_BLOCK, 0, stream>>>(counts, bsums, N);
        scan_bsums_kernel<<<1, 64, 0, stream>>>(bsums, nb);
        scan_final_kernel<<<nb, SCAN_BLOCK, 0, stream>>>(counts, bsums, offsets, cursors, N, E);
        scatter_ids_kernel<<<egrid, 256, 0, stream>>>(dst, cursors, eids, E);
        accum_ids_kernel<<<N, US, 0, stream>>>(x, sh, src, offsets, eids, out);
    } else {
        hipMemsetAsync(out, 0, sizeof(float) * (size_t)out_size, stream);
        atomic_kernel<<<E, US, 0, stream>>>(x, sh, src, dst, out, E);
    }
}

// Round 5
// 306.523 us; speedup vs baseline: 8.2113x; 1.8382x over previous
//
#include <hip/hip_runtime.h>

// out[n, u*4+s] = sum_{e: dst[e]==n} x[src[e], u] * sh[e, s]
// N=100000, U=32, S=4, E=3200000.
//
// R4 lesson: single-level scatter into a 64MB random-position region = 4.6x
// HBM write amplification (297MB observed). Fix: two-level radix partition.
//   1) coarse: 782 buckets x 128 nodes, per-block LDS hist + chunk reserve,
//      payload compressed to 12B/edge (bf16x4 sh + packed dst_local|src).
//   2) fine: one block per bucket, stage bucket in LDS (61.5KB), per-node
//      count + scan in LDS (writes offsets[] too - no global hist/scan),
//      scatter back IN-PLACE to the same global range (L2-local writes).
//   3) accum: one 128-thread block per node, register accumulation, unroll 4.
// R2 lesson kept: no bulk LDS float atomics (1 lane/cycle serial floor).

#define U_DIM 32
#define S_DIM 4
#define US 128
#define LOG_NPBK 7
#define NPBK 128              // nodes per coarse bucket
#define CAP 5120              // LDS-staged edges per bucket (mean 4096, sigma 64)
#define SPILL_E 1000000       // global spill for >CAP buckets (memory-safety)
#define CH_CHUNK 32           // edges per thread in coarse kernels

__device__ inline unsigned f2bf(float f) {          // RNE float->bf16 bits
    unsigned u = __float_as_uint(f);
    return (u + 0x7FFF + ((u >> 16) & 1)) >> 16;
}
__device__ inline float bf_extract(uint2 q, int s) {
    unsigned w = (s & 2) ? q.y : q.x;
    unsigned hw = (s & 1) ? (w >> 16) : (w & 0xFFFFu);
    return __uint_as_float(hw << 16);
}

__global__ void __launch_bounds__(256) coarse_hist_kernel(
        const int* __restrict__ dst, int* __restrict__ ccount, int E, int K) {
    __shared__ int h[1024];
    for (int b = threadIdx.x; b < K; b += 256) h[b] = 0;
    __syncthreads();
    int base = blockIdx.x * (256 * CH_CHUNK);
    for (int j = 0; j < CH_CHUNK; ++j) {
        int e = base + j * 256 + threadIdx.x;
        if (e < E) atomicAdd(&h[dst[e] >> LOG_NPBK], 1);
    }
    __syncthreads();
    for (int b = threadIdx.x; b < K; b += 256)
        if (h[b]) atomicAdd(&ccount[b], h[b]);
}

__global__ void __launch_bounds__(1024) coarse_scan_kernel(
        const int* __restrict__ ccount, int* __restrict__ cbase,
        int* __restrict__ ccur, int* __restrict__ offsets,
        int* __restrict__ spill_cursor, int K, int N, int E) {
    __shared__ int sc[1024];
    int t = threadIdx.x;
    int v = (t < K) ? ccount[t] : 0;
    sc[t] = v;
    __syncthreads();
    for (int off = 1; off < 1024; off <<= 1) {
        int w = (t >= off) ? sc[t - off] : 0;
        __syncthreads();
        sc[t] += w;
        __syncthreads();
    }
    if (t < K) { int ex = sc[t] - v; cbase[t] = ex; ccur[t] = ex; }
    if (t == 0) { cbase[K] = E; offsets[N] = E; *spill_cursor = 0; }
}

__global__ void __launch_bounds__(256) coarse_scatter_kernel(
        const int* __restrict__ dst, const int* __restrict__ src,
        const float4* __restrict__ sh, int* __restrict__ ccur,
        uint2* __restrict__ pay8, int* __restrict__ packed, int E, int K) {
    __shared__ int h[1024];
    __shared__ int cur[1024];
    for (int b = threadIdx.x; b < K; b += 256) h[b] = 0;
    __syncthreads();
    int base = blockIdx.x * (256 * CH_CHUNK);
    for (int j = 0; j < CH_CHUNK; ++j) {
        int e = base + j * 256 + threadIdx.x;
        if (e < E) atomicAdd(&h[dst[e] >> LOG_NPBK], 1);
    }
    __syncthreads();
    for (int b = threadIdx.x; b < K; b += 256)
        cur[b] = h[b] ? atomicAdd(&ccur[b], h[b]) : 0;   // contiguous chunk per bucket per block
    __syncthreads();
    for (int j = 0; j < CH_CHUNK; ++j) {
        int e = base + j * 256 + threadIdx.x;
        if (e < E) {
            int d = dst[e];
            int b = d >> LOG_NPBK;
            int pos = atomicAdd(&cur[b], 1);
            float4 s4 = sh[e];
            pay8[pos] = make_uint2(f2bf(s4.x) | (f2bf(s4.y) << 16),
                                   f2bf(s4.z) | (f2bf(s4.w) << 16));
            packed[pos] = ((d & (NPBK - 1)) << 24) | src[e];
        }
    }
}

// One block per coarse bucket: stage to LDS, per-node count+scan (emits
// offsets[]), then scatter back sorted IN-PLACE into [cbeg, cend).
__global__ void __launch_bounds__(512) fine_sort_kernel(
        const int* __restrict__ cbase, int* __restrict__ offsets,
        uint2* __restrict__ pay8, int* __restrict__ packed,
        uint2* __restrict__ spill_pay, int* __restrict__ spill_pk,
        int* __restrict__ spill_cursor, int N) {
    __shared__ uint2 spay[CAP];       // 40 KB
    __shared__ int   spk[CAP];        // 20 KB
    __shared__ int   cnt_[NPBK];
    __shared__ int   sc[NPBK];
    __shared__ int   sbase_s;
    int b = blockIdx.x;
    int t = threadIdx.x;
    int cbeg = cbase[b], cend = cbase[b + 1];
    int cnt = cend - cbeg;
    if (t == 0) sbase_s = (cnt > CAP) ? atomicAdd(spill_cursor, cnt - CAP) : 0;
    if (t < NPBK) cnt_[t] = 0;
    __syncthreads();
    for (int i = t; i < cnt; i += 512) {
        int pk = packed[cbeg + i];
        uint2 p8 = pay8[cbeg + i];
        atomicAdd(&cnt_[(pk >> 24) & (NPBK - 1)], 1);
        if (i < CAP) { spk[i] = pk; spay[i] = p8; }
        else {
            int sp = sbase_s + (i - CAP);
            if (sp < SPILL_E) { spill_pk[sp] = pk; spill_pay[sp] = p8; }
        }
    }
    __syncthreads();
    int v = (t < NPBK) ? cnt_[t] : 0;
    if (t < NPBK) sc[t] = v;
    __syncthreads();
    for (int off = 1; off < NPBK; off <<= 1) {
        int w = (t < NPBK && t >= off) ? sc[t - off] : 0;
        __syncthreads();
        if (t < NPBK) sc[t] += w;
        __syncthreads();
    }
    if (t < NPBK) {
        int ex = sc[t] - v;
        int node = (b << LOG_NPBK) + t;
        if (node <= N) offsets[node] = cbeg + ex;
        cnt_[t] = ex;                 // reuse as cursor
    }
    __syncthreads();
    for (int i = t; i < cnt; i += 512) {
        int pk; uint2 p8;
        bool ok = true;
        if (i < CAP) { pk = spk[i]; p8 = spay[i]; }
        else {
            int sp = sbase_s + (i - CAP);
            ok = (sp < SPILL_E);
            if (ok) { pk = spill_pk[sp]; p8 = spill_pay[sp]; }
        }
        if (ok) {
            int pos = cbeg + atomicAdd(&cnt_[(pk >> 24) & (NPBK - 1)], 1);
            packed[pos] = pk;
            pay8[pos] = p8;
        }
    }
}

// One block per node, 128 threads, thread t owns (u = t>>2, s = t&3).
__global__ void __launch_bounds__(US) accum_kernel(
        const float* __restrict__ x, const uint2* __restrict__ pay8,
        const int* __restrict__ packed, const int* __restrict__ offsets,
        float* __restrict__ out) {
    int n = blockIdx.x;
    int t = threadIdx.x;
    int u = t >> 2, s = t & 3;
    int beg = offsets[n], end = offsets[n + 1];
    float a0 = 0.f, a1 = 0.f, a2 = 0.f, a3 = 0.f;
    int i = beg;
    for (; i + 3 < end; i += 4) {
        int p0 = packed[i], p1 = packed[i + 1], p2 = packed[i + 2], p3 = packed[i + 3];
        uint2 q0 = pay8[i], q1 = pay8[i + 1], q2 = pay8[i + 2], q3 = pay8[i + 3];
        a0 += x[(p0 & 0xFFFFFF) * U_DIM + u] * bf_extract(q0, s);
        a1 += x[(p1 & 0xFFFFFF) * U_DIM + u] * bf_extract(q1, s);
        a2 += x[(p2 & 0xFFFFFF) * U_DIM + u] * bf_extract(q2, s);
        a3 += x[(p3 & 0xFFFFFF) * U_DIM + u] * bf_extract(q3, s);
    }
    for (; i < end; ++i)
        a0 += x[(packed[i] & 0xFFFFFF) * U_DIM + u] * bf_extract(pay8[i], s);
    out[(size_t)n * US + t] = (a0 + a1) + (a2 + a3);
}

// --- Fallback tier 1: sorted edge-id list (global hist + 3-level scan) ---
constexpr int SCAN_BLOCK = 256;
constexpr int SCAN_ITEMS = 8;
constexpr int SCAN_CHUNK = SCAN_BLOCK * SCAN_ITEMS;

__global__ void __launch_bounds__(256) hist_kernel(
        const int* __restrict__ dst, int* __restrict__ counts, int E) {
    int e = blockIdx.x * blockDim.x + threadIdx.x;
    if (e < E) atomicAdd(&counts[dst[e]], 1);
}
__global__ void __launch_bounds__(SCAN_BLOCK) block_sum_kernel(
        const int* __restrict__ counts, int* __restrict__ bsums, int N) {
    __shared__ int sdata[SCAN_BLOCK];
    int base = blockIdx.x * SCAN_CHUNK;
    int sum = 0;
    for (int j = 0; j < SCAN_ITEMS; ++j) {
        int idx = base + j * SCAN_BLOCK + threadIdx.x;
        if (idx < N) sum += counts[idx];
    }
    sdata[threadIdx.x] = sum;
    __syncthreads();
    for (int off = SCAN_BLOCK / 2; off > 0; off >>= 1) {
        if (threadIdx.x < off) sdata[threadIdx.x] += sdata[threadIdx.x + off];
        __syncthreads();
    }
    if (threadIdx.x == 0) bsums[blockIdx.x] = sdata[0];
}
__global__ void scan_bsums_kernel(int* __restrict__ bsums, int nb) {
    if (threadIdx.x == 0 && blockIdx.x == 0) {
        int acc = 0;
        for (int i = 0; i < nb; ++i) { int v = bsums[i]; bsums[i] = acc; acc += v; }
    }
}
__global__ void __launch_bounds__(SCAN_BLOCK) scan_final_kernel(
        const int* __restrict__ counts, const int* __restrict__ bsums,
        int* __restrict__ offsets, int* __restrict__ cursors, int N, int E) {
    __shared__ int sdata[SCAN_BLOCK];
    int base = blockIdx.x * SCAN_CHUNK + threadIdx.x * SCAN_ITEMS;
    int local[SCAN_ITEMS];
    int tsum = 0;
    for (int j = 0; j < SCAN_ITEMS; ++j) {
        int idx = base + j;
        int v = (idx < N) ? counts[idx] : 0;
        local[j] = tsum;
        tsum += v;
    }
    sdata[threadIdx.x] = tsum;
    __syncthreads();
    for (int off = 1; off < SCAN_BLOCK; off <<= 1) {
        int v = (threadIdx.x >= off) ? sdata[threadIdx.x - off] : 0;
        __syncthreads();
        sdata[threadIdx.x] += v;
        __syncthreads();
    }
    int excl = sdata[threadIdx.x] - tsum + bsums[blockIdx.x];
    for (int j = 0; j < SCAN_ITEMS; ++j) {
        int idx = base + j;
        if (idx < N) { int o = excl + local[j]; offsets[idx] = o; cursors[idx] = o; }
    }
    if (blockIdx.x == 0 && threadIdx.x == 0) offsets[N] = E;
}
__global__ void __launch_bounds__(256) scatter_ids_kernel(
        const int* __restrict__ dst, int* __restrict__ cursors,
        int* __restrict__ eids, int E) {
    int e = blockIdx.x * blockDim.x + threadIdx.x;
    if (e < E) { int pos = atomicAdd(&cursors[dst[e]], 1); eids[pos] = e; }
}
__global__ void __launch_bounds__(US) accum_ids_kernel(
        const float* __restrict__ x, const float* __restrict__ sh,
        const int* __restrict__ src, const int* __restrict__ offsets,
        const int* __restrict__ eids, float* __restrict__ out) {
    int n = blockIdx.x;
    int t = threadIdx.x;
    int u = t >> 2, s = t & 3;
    int beg = offsets[n], end = offsets[n + 1];
    float acc = 0.f;
    for (int i = beg; i < end; ++i) {
        int e = eids[i];
        acc += x[src[e] * U_DIM + u] * sh[e * S_DIM + s];
    }
    out[(size_t)n * US + t] = acc;
}
__global__ void __launch_bounds__(US) atomic_kernel(
        const float* __restrict__ x, const float* __restrict__ sh,
        const int* __restrict__ src, const int* __restrict__ dst,
        float* __restrict__ out, int E) {
    int e = blockIdx.x;
    int t = threadIdx.x;
    float v = x[src[e] * U_DIM + (t >> 2)] * sh[e * S_DIM + (t & 3)];
    atomicAdd(&out[(size_t)dst[e] * US + t], v);
}

extern "C" void kernel_launch(void* const* d_in, const int* in_sizes, int n_in,
                              void* d_out, int out_size, void* d_ws, size_t ws_size,
                              hipStream_t stream) {
    const float* x  = (const float*)d_in[0];
    const float* sh = (const float*)d_in[1];
    const int* src  = (const int*)d_in[2];
    const int* dst  = (const int*)d_in[3];
    float* out = (float*)d_out;

    const int E = in_sizes[2];
    const int N = in_sizes[0] / U_DIM;
    const int K = (N + NPBK - 1) >> LOG_NPBK;
    const int cgrid = (E + 256 * CH_CHUNK - 1) / (256 * CH_CHUNK);
    const int egrid = (E + 255) / 256;
    const int nb = (N + SCAN_CHUNK - 1) / SCAN_CHUNK;

    // Primary: pay8 uint2[E] | spill_pay uint2[SPILL_E] | packed int[E] |
    //          spill_pk int[SPILL_E] | offsets[N+1] | ccount[K] | cbase[K+1] |
    //          ccur[K] | spill_cursor[1]
    size_t need_main = (size_t)E * 8 + (size_t)SPILL_E * 8 + (size_t)E * 4 +
                       (size_t)SPILL_E * 4 + (size_t)(N + 1) * 4 +
                       (size_t)(3 * K + 2) * 4;
    size_t need_ids = (size_t)E * 4 + (size_t)(3 * N + 1 + nb) * 4;

    if (K <= 1024 && ws_size >= need_main) {
        uint2* pay8      = (uint2*)d_ws;
        uint2* spill_pay = pay8 + E;
        int* packed      = (int*)(spill_pay + SPILL_E);
        int* spill_pk    = packed + E;
        int* offsets     = spill_pk + SPILL_E;
        int* ccount      = offsets + N + 1;
        int* cbase       = ccount + K;
        int* ccur        = cbase + K + 1;
        int* spill_cur   = ccur + K;

        hipMemsetAsync(ccount, 0, sizeof(int) * (size_t)K, stream);
        coarse_hist_kernel<<<cgrid, 256, 0, stream>>>(dst, ccount, E, K);
        coarse_scan_kernel<<<1, 1024, 0, stream>>>(ccount, cbase, ccur, offsets,
                                                   spill_cur, K, N, E);
        coarse_scatter_kernel<<<cgrid, 256, 0, stream>>>(dst, src, (const float4*)sh,
                                                         ccur, pay8, packed, E, K);
        fine_sort_kernel<<<K, 512, 0, stream>>>(cbase, offsets, pay8, packed,
                                                spill_pay, spill_pk, spill_cur, N);
        accum_kernel<<<N, US, 0, stream>>>(x, pay8, packed, offsets, out);
    } else if (ws_size >= need_ids) {
        int* eids    = (int*)d_ws;
        int* counts  = eids + E;
        int* offsets = counts + N;
        int* cursors = offsets + N + 1;
        int* bsums   = cursors + N;

        hipMemsetAsync(counts, 0, sizeof(int) * (size_t)N, stream);
        hist_kernel<<<egrid, 256, 0, stream>>>(dst, counts, E);
        block_sum_kernel<<<nb, SCAN_BLOCK, 0, stream>>>(counts, bsums, N);
        scan_bsums_kernel<<<1, 64, 0, stream>>>(bsums, nb);
        scan_final_kernel<<<nb, SCAN_BLOCK, 0, stream>>>(counts, bsums, offsets, cursors, N, E);
        scatter_ids_kernel<<<egrid, 256, 0, stream>>>(dst, cursors, eids, E);
        accum_ids_kernel<<<N, US, 0, stream>>>(x, sh, src, offsets, eids, out);
    } else {
        hipMemsetAsync(out, 0, sizeof(float) * (size_t)out_size, stream);
        atomic_kernel<<<E, US, 0, stream>>>(x, sh, src, dst, out, E);
    }
}

// Round 6
// 285.999 us; speedup vs baseline: 8.8005x; 1.0718x over previous
//
#include <hip/hip_runtime.h>

// out[n, u*4+s] = sum_{e: dst[e]==n} x[src[e], u] * sh[e, s]
// N=100000, U=32, S=4, E=3200000.
//
// R4/R5 lesson: scattered partial-line writes across a 38MB region from many
// blocks/XCDs = 4.6x HBM write amplification. Run length per (bucket,block)
// = E/(nblocks*K) must be >= ~16 edges. R6: 256 coarse blocks (runs of 16),
// per-(bucket,block) chunk bases PRECOMPUTED (hist -> cnt[b][i] table ->
// per-bucket scan), so scatter does only ONE LDS atomic per edge.
// R2 lesson kept: no bulk LDS float atomics in accum (register accumulation).

#define U_DIM 32
#define S_DIM 4
#define US 128
#define LOG_NPBK 7
#define NPBK 128              // nodes per bucket
#define MAXK 1024
#define NBLK 256              // coarse partition blocks
#define CAP 5120              // LDS-staged edges per bucket (mean 4096, sigma 64)
#define SPILL_E 1000000       // global spill for >CAP buckets (memory-safety)

__device__ inline unsigned f2bf(float f) {          // RNE float->bf16 bits
    unsigned u = __float_as_uint(f);
    return (u + 0x7FFF + ((u >> 16) & 1)) >> 16;
}
__device__ inline float bf_extract(uint2 q, int s) {
    unsigned w = (s & 2) ? q.y : q.x;
    unsigned hw = (s & 1) ? (w >> 16) : (w & 0xFFFFu);
    return __uint_as_float(hw << 16);
}

// Per-block histogram -> cnt[b*NBLK + block] (b-major for coalesced scan) and
// global bucket totals via atomics.
__global__ void __launch_bounds__(256) coarse_hist_kernel(
        const int* __restrict__ dst, int* __restrict__ ccount,
        int* __restrict__ cnt, int E, int K, int EPB) {
    __shared__ int h[MAXK];
    for (int b = threadIdx.x; b < K; b += 256) h[b] = 0;
    __syncthreads();
    int base = blockIdx.x * EPB;
    int lim = min(EPB, E - base);
    for (int i = threadIdx.x; i < lim; i += 256)
        atomicAdd(&h[dst[base + i] >> LOG_NPBK], 1);
    __syncthreads();
    for (int b = threadIdx.x; b < K; b += 256) {
        int c = h[b];
        cnt[b * NBLK + blockIdx.x] = c;
        if (c) atomicAdd(&ccount[b], c);
    }
}

__global__ void __launch_bounds__(1024) coarse_scan_kernel(
        const int* __restrict__ ccount, int* __restrict__ cbase,
        int* __restrict__ offsets, int* __restrict__ spill_cursor,
        int K, int N, int E) {
    __shared__ int sc[1024];
    int t = threadIdx.x;
    int v = (t < K) ? ccount[t] : 0;
    sc[t] = v;
    __syncthreads();
    for (int off = 1; off < 1024; off <<= 1) {
        int w = (t >= off) ? sc[t - off] : 0;
        __syncthreads();
        sc[t] += w;
        __syncthreads();
    }
    if (t < K) cbase[t] = sc[t] - v;
    if (t == 0) { cbase[K] = E; offsets[N] = E; *spill_cursor = 0; }
}

// One block per bucket: exclusive scan of cnt[b][0..NBLK) -> base_tab[b][i].
__global__ void __launch_bounds__(NBLK) chunk_base_kernel(
        const int* __restrict__ cnt, const int* __restrict__ cbase,
        int* __restrict__ base_tab) {
    __shared__ int sc[NBLK];
    int b = blockIdx.x;
    int t = threadIdx.x;
    int v = cnt[b * NBLK + t];
    sc[t] = v;
    __syncthreads();
    for (int off = 1; off < NBLK; off <<= 1) {
        int w = (t >= off) ? sc[t - off] : 0;
        __syncthreads();
        sc[t] += w;
        __syncthreads();
    }
    base_tab[b * NBLK + t] = cbase[b] + sc[t] - v;
}

__global__ void __launch_bounds__(256) coarse_scatter_kernel(
        const int* __restrict__ dst, const int* __restrict__ src,
        const float4* __restrict__ sh, const int* __restrict__ base_tab,
        uint2* __restrict__ pay8, int* __restrict__ packed,
        int E, int K, int EPB) {
    __shared__ int cur[MAXK];
    for (int b = threadIdx.x; b < K; b += 256)
        cur[b] = base_tab[b * NBLK + blockIdx.x];
    __syncthreads();
    int base = blockIdx.x * EPB;
    int lim = min(EPB, E - base);
    for (int i = threadIdx.x; i < lim; i += 256) {
        int e = base + i;
        int d = dst[e];
        int b = d >> LOG_NPBK;
        int pos = atomicAdd(&cur[b], 1);          // single LDS atomic per edge
        float4 s4 = sh[e];
        pay8[pos] = make_uint2(f2bf(s4.x) | (f2bf(s4.y) << 16),
                               f2bf(s4.z) | (f2bf(s4.w) << 16));
        packed[pos] = ((d & (NPBK - 1)) << 24) | src[e];
    }
}

// One block per coarse bucket: stage to LDS, per-node count+scan (emits
// offsets[]), then scatter back sorted IN-PLACE into [cbeg, cend).
__global__ void __launch_bounds__(512) fine_sort_kernel(
        const int* __restrict__ cbase, int* __restrict__ offsets,
        uint2* __restrict__ pay8, int* __restrict__ packed,
        uint2* __restrict__ spill_pay, int* __restrict__ spill_pk,
        int* __restrict__ spill_cursor, int N) {
    __shared__ uint2 spay[CAP];       // 40 KB
    __shared__ int   spk[CAP];        // 20 KB
    __shared__ int   cnt_[NPBK];
    __shared__ int   sc[NPBK];
    __shared__ int   sbase_s;
    int b = blockIdx.x;
    int t = threadIdx.x;
    int cbeg = cbase[b], cend = cbase[b + 1];
    int cnt = cend - cbeg;
    if (t == 0) sbase_s = (cnt > CAP) ? atomicAdd(spill_cursor, cnt - CAP) : 0;
    if (t < NPBK) cnt_[t] = 0;
    __syncthreads();
    for (int i = t; i < cnt; i += 512) {
        int pk = packed[cbeg + i];
        uint2 p8 = pay8[cbeg + i];
        atomicAdd(&cnt_[(pk >> 24) & (NPBK - 1)], 1);
        if (i < CAP) { spk[i] = pk; spay[i] = p8; }
        else {
            int sp = sbase_s + (i - CAP);
            if (sp < SPILL_E) { spill_pk[sp] = pk; spill_pay[sp] = p8; }
        }
    }
    __syncthreads();
    int v = (t < NPBK) ? cnt_[t] : 0;
    if (t < NPBK) sc[t] = v;
    __syncthreads();
    for (int off = 1; off < NPBK; off <<= 1) {
        int w = (t < NPBK && t >= off) ? sc[t - off] : 0;
        __syncthreads();
        if (t < NPBK) sc[t] += w;
        __syncthreads();
    }
    if (t < NPBK) {
        int ex = sc[t] - v;
        int node = (b << LOG_NPBK) + t;
        if (node <= N) offsets[node] = cbeg + ex;
        cnt_[t] = ex;                 // reuse as cursor
    }
    __syncthreads();
    for (int i = t; i < cnt; i += 512) {
        int pk; uint2 p8;
        bool ok = true;
        if (i < CAP) { pk = spk[i]; p8 = spay[i]; }
        else {
            int sp = sbase_s + (i - CAP);
            ok = (sp < SPILL_E);
            if (ok) { pk = spill_pk[sp]; p8 = spill_pay[sp]; }
        }
        if (ok) {
            int pos = cbeg + atomicAdd(&cnt_[(pk >> 24) & (NPBK - 1)], 1);
            packed[pos] = pk;
            pay8[pos] = p8;
        }
    }
}

// One block per node, 128 threads, thread t owns (u = t>>2, s = t&3).
__global__ void __launch_bounds__(US) accum_kernel(
        const float* __restrict__ x, const uint2* __restrict__ pay8,
        const int* __restrict__ packed, const int* __restrict__ offsets,
        float* __restrict__ out) {
    int n = blockIdx.x;
    int t = threadIdx.x;
    int u = t >> 2, s = t & 3;
    int beg = offsets[n], end = offsets[n + 1];
    float a0 = 0.f, a1 = 0.f, a2 = 0.f, a3 = 0.f;
    int i = beg;
    for (; i + 3 < end; i += 4) {
        int p0 = packed[i], p1 = packed[i + 1], p2 = packed[i + 2], p3 = packed[i + 3];
        uint2 q0 = pay8[i], q1 = pay8[i + 1], q2 = pay8[i + 2], q3 = pay8[i + 3];
        a0 += x[(p0 & 0xFFFFFF) * U_DIM + u] * bf_extract(q0, s);
        a1 += x[(p1 & 0xFFFFFF) * U_DIM + u] * bf_extract(q1, s);
        a2 += x[(p2 & 0xFFFFFF) * U_DIM + u] * bf_extract(q2, s);
        a3 += x[(p3 & 0xFFFFFF) * U_DIM + u] * bf_extract(q3, s);
    }
    for (; i < end; ++i)
        a0 += x[(packed[i] & 0xFFFFFF) * U_DIM + u] * bf_extract(pay8[i], s);
    out[(size_t)n * US + t] = (a0 + a1) + (a2 + a3);
}

// --- Fallback tier 1: sorted edge-id list (global hist + 3-level scan) ---
constexpr int SCAN_BLOCK = 256;
constexpr int SCAN_ITEMS = 8;
constexpr int SCAN_CHUNK = SCAN_BLOCK * SCAN_ITEMS;

__global__ void __launch_bounds__(256) hist_kernel(
        const int* __restrict__ dst, int* __restrict__ counts, int E) {
    int e = blockIdx.x * blockDim.x + threadIdx.x;
    if (e < E) atomicAdd(&counts[dst[e]], 1);
}
__global__ void __launch_bounds__(SCAN_BLOCK) block_sum_kernel(
        const int* __restrict__ counts, int* __restrict__ bsums, int N) {
    __shared__ int sdata[SCAN_BLOCK];
    int base = blockIdx.x * SCAN_CHUNK;
    int sum = 0;
    for (int j = 0; j < SCAN_ITEMS; ++j) {
        int idx = base + j * SCAN_BLOCK + threadIdx.x;
        if (idx < N) sum += counts[idx];
    }
    sdata[threadIdx.x] = sum;
    __syncthreads();
    for (int off = SCAN_BLOCK / 2; off > 0; off >>= 1) {
        if (threadIdx.x < off) sdata[threadIdx.x] += sdata[threadIdx.x + off];
        __syncthreads();
    }
    if (threadIdx.x == 0) bsums[blockIdx.x] = sdata[0];
}
__global__ void scan_bsums_kernel(int* __restrict__ bsums, int nb) {
    if (threadIdx.x == 0 && blockIdx.x == 0) {
        int acc = 0;
        for (int i = 0; i < nb; ++i) { int v = bsums[i]; bsums[i] = acc; acc += v; }
    }
}
__global__ void __launch_bounds__(SCAN_BLOCK) scan_final_kernel(
        const int* __restrict__ counts, const int* __restrict__ bsums,
        int* __restrict__ offsets, int* __restrict__ cursors, int N, int E) {
    __shared__ int sdata[SCAN_BLOCK];
    int base = blockIdx.x * SCAN_CHUNK + threadIdx.x * SCAN_ITEMS;
    int local[SCAN_ITEMS];
    int tsum = 0;
    for (int j = 0; j < SCAN_ITEMS; ++j) {
        int idx = base + j;
        int v = (idx < N) ? counts[idx] : 0;
        local[j] = tsum;
        tsum += v;
    }
    sdata[threadIdx.x] = tsum;
    __syncthreads();
    for (int off = 1; off < SCAN_BLOCK; off <<= 1) {
        int v = (threadIdx.x >= off) ? sdata[threadIdx.x - off] : 0;
        __syncthreads();
        sdata[threadIdx.x] += v;
        __syncthreads();
    }
    int excl = sdata[threadIdx.x] - tsum + bsums[blockIdx.x];
    for (int j = 0; j < SCAN_ITEMS; ++j) {
        int idx = base + j;
        if (idx < N) { int o = excl + local[j]; offsets[idx] = o; cursors[idx] = o; }
    }
    if (blockIdx.x == 0 && threadIdx.x == 0) offsets[N] = E;
}
__global__ void __launch_bounds__(256) scatter_ids_kernel(
        const int* __restrict__ dst, int* __restrict__ cursors,
        int* __restrict__ eids, int E) {
    int e = blockIdx.x * blockDim.x + threadIdx.x;
    if (e < E) { int pos = atomicAdd(&cursors[dst[e]], 1); eids[pos] = e; }
}
__global__ void __launch_bounds__(US) accum_ids_kernel(
        const float* __restrict__ x, const float* __restrict__ sh,
        const int* __restrict__ src, const int* __restrict__ offsets,
        const int* __restrict__ eids, float* __restrict__ out) {
    int n = blockIdx.x;
    int t = threadIdx.x;
    int u = t >> 2, s = t & 3;
    int beg = offsets[n], end = offsets[n + 1];
    float acc = 0.f;
    for (int i = beg; i < end; ++i) {
        int e = eids[i];
        acc += x[src[e] * U_DIM + u] * sh[e * S_DIM + s];
    }
    out[(size_t)n * US + t] = acc;
}
__global__ void __launch_bounds__(US) atomic_kernel(
        const float* __restrict__ x, const float* __restrict__ sh,
        const int* __restrict__ src, const int* __restrict__ dst,
        float* __restrict__ out, int E) {
    int e = blockIdx.x;
    int t = threadIdx.x;
    float v = x[src[e] * U_DIM + (t >> 2)] * sh[e * S_DIM + (t & 3)];
    atomicAdd(&out[(size_t)dst[e] * US + t], v);
}

extern "C" void kernel_launch(void* const* d_in, const int* in_sizes, int n_in,
                              void* d_out, int out_size, void* d_ws, size_t ws_size,
                              hipStream_t stream) {
    const float* x  = (const float*)d_in[0];
    const float* sh = (const float*)d_in[1];
    const int* src  = (const int*)d_in[2];
    const int* dst  = (const int*)d_in[3];
    float* out = (float*)d_out;

    const int E = in_sizes[2];
    const int N = in_sizes[0] / U_DIM;
    const int K = (N + NPBK - 1) >> LOG_NPBK;
    const int EPB = (E + NBLK - 1) / NBLK;
    const int egrid = (E + 255) / 256;
    const int nb = (N + SCAN_CHUNK - 1) / SCAN_CHUNK;

    // Primary: pay8 uint2[E] | spill_pay uint2[SPILL_E] | packed int[E] |
    //          spill_pk int[SPILL_E] | offsets[N+1] | ccount[K] | cbase[K+1] |
    //          cnt[K*NBLK] | base_tab[K*NBLK] | spill_cursor[1]
    size_t need_main = (size_t)E * 8 + (size_t)SPILL_E * 8 + (size_t)E * 4 +
                       (size_t)SPILL_E * 4 + (size_t)(N + 1) * 4 +
                       (size_t)(2 * K + 2) * 4 + (size_t)(2 * K * NBLK) * 4;
    size_t need_ids = (size_t)E * 4 + (size_t)(3 * N + 1 + nb) * 4;

    if (K <= MAXK && ws_size >= need_main) {
        uint2* pay8      = (uint2*)d_ws;
        uint2* spill_pay = pay8 + E;
        int* packed      = (int*)(spill_pay + SPILL_E);
        int* spill_pk    = packed + E;
        int* offsets     = spill_pk + SPILL_E;
        int* ccount      = offsets + N + 1;
        int* cbase       = ccount + K;
        int* cnt         = cbase + K + 1;
        int* base_tab    = cnt + K * NBLK;
        int* spill_cur   = base_tab + K * NBLK;

        hipMemsetAsync(ccount, 0, sizeof(int) * (size_t)K, stream);
        coarse_hist_kernel<<<NBLK, 256, 0, stream>>>(dst, ccount, cnt, E, K, EPB);
        coarse_scan_kernel<<<1, 1024, 0, stream>>>(ccount, cbase, offsets,
                                                   spill_cur, K, N, E);
        chunk_base_kernel<<<K, NBLK, 0, stream>>>(cnt, cbase, base_tab);
        coarse_scatter_kernel<<<NBLK, 256, 0, stream>>>(dst, src, (const float4*)sh,
                                                        base_tab, pay8, packed,
                                                        E, K, EPB);
        fine_sort_kernel<<<K, 512, 0, stream>>>(cbase, offsets, pay8, packed,
                                                spill_pay, spill_pk, spill_cur, N);
        accum_kernel<<<N, US, 0, stream>>>(x, pay8, packed, offsets, out);
    } else if (ws_size >= need_ids) {
        int* eids    = (int*)d_ws;
        int* counts  = eids + E;
        int* offsets = counts + N;
        int* cursors = offsets + N + 1;
        int* bsums   = cursors + N;

        hipMemsetAsync(counts, 0, sizeof(int) * (size_t)N, stream);
        hist_kernel<<<egrid, 256, 0, stream>>>(dst, counts, E);
        block_sum_kernel<<<nb, SCAN_BLOCK, 0, stream>>>(counts, bsums, N);
        scan_bsums_kernel<<<1, 64, 0, stream>>>(bsums, nb);
        scan_final_kernel<<<nb, SCAN_BLOCK, 0, stream>>>(counts, bsums, offsets, cursors, N, E);
        scatter_ids_kernel<<<egrid, 256, 0, stream>>>(dst, cursors, eids, E);
        accum_ids_kernel<<<N, US, 0, stream>>>(x, sh, src, offsets, eids, out);
    } else {
        hipMemsetAsync(out, 0, sizeof(float) * (size_t)out_size, stream);
        atomic_kernel<<<E, US, 0, stream>>>(x, sh, src, dst, out, E);
    }
}

// Round 7
// 251.363 us; speedup vs baseline: 10.0132x; 1.1378x over previous
//
#include <hip/hip_runtime.h>

// out[n, u*4+s] = sum_{e: dst[e]==n} x[src[e], u] * sh[e, s]
// N=100000, U=32, S=4, E=3200000.
//
// R4/R5: scattered partial-line writes = 4.6x HBM write amp -> two-level
//   partition, run length per (bucket,chunk) >= 16 edges.
// R6: coarse_scatter was latency-bound (256 blocks = 4 waves/CU, 10.6% occ)
//   -> keep 256 chunks but 1024 threads each (16 waves/CU, same write runs).
//   accum: x -> bf16 (64B/row gather) + thread remap (t -> u=t&31, g=t>>5,
//   acc[4] per thread, 4 FMAs/edge) to cut VALU ~2.5x and halve x traffic.
// R2 kept: no bulk LDS float atomics (register accumulation only).

#define U_DIM 32
#define S_DIM 4
#define US 128
#define LOG_NPBK 7
#define NPBK 128              // nodes per bucket
#define MAXK 1024
#define NBLK 256              // coarse partition chunks
#define CAP 5120              // LDS-staged edges per bucket (mean 4096, sigma 64)
#define SPILL_E 1000000       // global spill for >CAP buckets (memory-safety)

__device__ inline unsigned f2bf(float f) {          // RNE float->bf16 bits
    unsigned u = __float_as_uint(f);
    return (u + 0x7FFF + ((u >> 16) & 1)) >> 16;
}

// x (f32) -> bf16 bits, vectorized.
__global__ void __launch_bounds__(256) xcvt_kernel(
        const float4* __restrict__ x4, ushort4* __restrict__ xb4, int n4) {
    int i = blockIdx.x * 256 + threadIdx.x;
    if (i < n4) {
        float4 v = x4[i];
        ushort4 r;
        r.x = (unsigned short)f2bf(v.x);
        r.y = (unsigned short)f2bf(v.y);
        r.z = (unsigned short)f2bf(v.z);
        r.w = (unsigned short)f2bf(v.w);
        xb4[i] = r;
    }
}

// Per-chunk histogram -> cnt[b*NBLK + chunk] (b-major) + global bucket totals.
__global__ void __launch_bounds__(1024) coarse_hist_kernel(
        const int* __restrict__ dst, int* __restrict__ ccount,
        int* __restrict__ cnt, int E, int K, int EPB) {
    __shared__ int h[MAXK];
    for (int b = threadIdx.x; b < K; b += 1024) h[b] = 0;
    __syncthreads();
    int base = blockIdx.x * EPB;
    int lim = min(EPB, E - base);
    for (int i = threadIdx.x; i < lim; i += 1024)
        atomicAdd(&h[dst[base + i] >> LOG_NPBK], 1);
    __syncthreads();
    for (int b = threadIdx.x; b < K; b += 1024) {
        int c = h[b];
        cnt[b * NBLK + blockIdx.x] = c;
        if (c) atomicAdd(&ccount[b], c);
    }
}

__global__ void __launch_bounds__(1024) coarse_scan_kernel(
        const int* __restrict__ ccount, int* __restrict__ cbase,
        int* __restrict__ offsets, int* __restrict__ spill_cursor,
        int K, int N, int E) {
    __shared__ int sc[1024];
    int t = threadIdx.x;
    int v = (t < K) ? ccount[t] : 0;
    sc[t] = v;
    __syncthreads();
    for (int off = 1; off < 1024; off <<= 1) {
        int w = (t >= off) ? sc[t - off] : 0;
        __syncthreads();
        sc[t] += w;
        __syncthreads();
    }
    if (t < K) cbase[t] = sc[t] - v;
    if (t == 0) { cbase[K] = E; offsets[N] = E; *spill_cursor = 0; }
}

// One block per bucket: exclusive scan of cnt[b][0..NBLK) -> base_tab[b][i].
__global__ void __launch_bounds__(NBLK) chunk_base_kernel(
        const int* __restrict__ cnt, const int* __restrict__ cbase,
        int* __restrict__ base_tab) {
    __shared__ int sc[NBLK];
    int b = blockIdx.x;
    int t = threadIdx.x;
    int v = cnt[b * NBLK + t];
    sc[t] = v;
    __syncthreads();
    for (int off = 1; off < NBLK; off <<= 1) {
        int w = (t >= off) ? sc[t - off] : 0;
        __syncthreads();
        sc[t] += w;
        __syncthreads();
    }
    base_tab[b * NBLK + t] = cbase[b] + sc[t] - v;
}

__global__ void __launch_bounds__(1024) coarse_scatter_kernel(
        const int* __restrict__ dst, const int* __restrict__ src,
        const float4* __restrict__ sh, const int* __restrict__ base_tab,
        uint2* __restrict__ pay8, int* __restrict__ packed,
        int E, int K, int EPB) {
    __shared__ int cur[MAXK];
    for (int b = threadIdx.x; b < K; b += 1024)
        cur[b] = base_tab[b * NBLK + blockIdx.x];
    __syncthreads();
    int base = blockIdx.x * EPB;
    int lim = min(EPB, E - base);
    for (int i = threadIdx.x; i < lim; i += 1024) {
        int e = base + i;
        int d = dst[e];
        int b = d >> LOG_NPBK;
        int pos = atomicAdd(&cur[b], 1);          // single LDS atomic per edge
        float4 s4 = sh[e];
        pay8[pos] = make_uint2(f2bf(s4.x) | (f2bf(s4.y) << 16),
                               f2bf(s4.z) | (f2bf(s4.w) << 16));
        packed[pos] = ((d & (NPBK - 1)) << 24) | src[e];
    }
}

// One block per coarse bucket: stage to LDS, per-node count+scan (emits
// offsets[]), then scatter back sorted IN-PLACE into [cbeg, cend).
__global__ void __launch_bounds__(512) fine_sort_kernel(
        const int* __restrict__ cbase, int* __restrict__ offsets,
        uint2* __restrict__ pay8, int* __restrict__ packed,
        uint2* __restrict__ spill_pay, int* __restrict__ spill_pk,
        int* __restrict__ spill_cursor, int N) {
    __shared__ uint2 spay[CAP];       // 40 KB
    __shared__ int   spk[CAP];        // 20 KB
    __shared__ int   cnt_[NPBK];
    __shared__ int   sc[NPBK];
    __shared__ int   sbase_s;
    int b = blockIdx.x;
    int t = threadIdx.x;
    int cbeg = cbase[b], cend = cbase[b + 1];
    int cnt = cend - cbeg;
    if (t == 0) sbase_s = (cnt > CAP) ? atomicAdd(spill_cursor, cnt - CAP) : 0;
    if (t < NPBK) cnt_[t] = 0;
    __syncthreads();
    for (int i = t; i < cnt; i += 512) {
        int pk = packed[cbeg + i];
        uint2 p8 = pay8[cbeg + i];
        atomicAdd(&cnt_[(pk >> 24) & (NPBK - 1)], 1);
        if (i < CAP) { spk[i] = pk; spay[i] = p8; }
        else {
            int sp = sbase_s + (i - CAP);
            if (sp < SPILL_E) { spill_pk[sp] = pk; spill_pay[sp] = p8; }
        }
    }
    __syncthreads();
    int v = (t < NPBK) ? cnt_[t] : 0;
    if (t < NPBK) sc[t] = v;
    __syncthreads();
    for (int off = 1; off < NPBK; off <<= 1) {
        int w = (t < NPBK && t >= off) ? sc[t - off] : 0;
        __syncthreads();
        if (t < NPBK) sc[t] += w;
        __syncthreads();
    }
    if (t < NPBK) {
        int ex = sc[t] - v;
        int node = (b << LOG_NPBK) + t;
        if (node <= N) offsets[node] = cbeg + ex;
        cnt_[t] = ex;                 // reuse as cursor
    }
    __syncthreads();
    for (int i = t; i < cnt; i += 512) {
        int pk; uint2 p8;
        bool ok = true;
        if (i < CAP) { pk = spk[i]; p8 = spay[i]; }
        else {
            int sp = sbase_s + (i - CAP);
            ok = (sp < SPILL_E);
            if (ok) { pk = spill_pk[sp]; p8 = spill_pay[sp]; }
        }
        if (ok) {
            int pos = cbeg + atomicAdd(&cnt_[(pk >> 24) & (NPBK - 1)], 1);
            packed[pos] = pk;
            pay8[pos] = p8;
        }
    }
}

// One block per node, 128 threads: t -> (u = t&31, edge-group g = t>>5).
// Each thread accumulates all 4 s in registers; x row read = one coalesced
// 64B bf16 line per edge; sh extraction = 1 shift/mask per s value.
__global__ void __launch_bounds__(US) accum_kernel(
        const unsigned short* __restrict__ xb, const uint2* __restrict__ pay8,
        const int* __restrict__ packed, const int* __restrict__ offsets,
        float* __restrict__ out) {
    int n = blockIdx.x;
    int t = threadIdx.x;
    int u = t & 31;
    int g = t >> 5;                   // 0..3
    int beg = offsets[n], end = offsets[n + 1];
    float a0 = 0.f, a1 = 0.f, a2 = 0.f, a3 = 0.f;
    int i = beg + g;
    for (; i + 4 < end; i += 8) {     // unroll 2 for MLP
        int pkA = packed[i], pkB = packed[i + 4];
        uint2 qA = pay8[i], qB = pay8[i + 4];
        float xA = __uint_as_float((unsigned)xb[(pkA & 0xFFFFFF) * U_DIM + u] << 16);
        float xB = __uint_as_float((unsigned)xb[(pkB & 0xFFFFFF) * U_DIM + u] << 16);
        a0 += xA * __uint_as_float(qA.x << 16);
        a1 += xA * __uint_as_float(qA.x & 0xFFFF0000u);
        a2 += xA * __uint_as_float(qA.y << 16);
        a3 += xA * __uint_as_float(qA.y & 0xFFFF0000u);
        a0 += xB * __uint_as_float(qB.x << 16);
        a1 += xB * __uint_as_float(qB.x & 0xFFFF0000u);
        a2 += xB * __uint_as_float(qB.y << 16);
        a3 += xB * __uint_as_float(qB.y & 0xFFFF0000u);
    }
    if (i < end) {
        int pk = packed[i];
        uint2 q = pay8[i];
        float xv = __uint_as_float((unsigned)xb[(pk & 0xFFFFFF) * U_DIM + u] << 16);
        a0 += xv * __uint_as_float(q.x << 16);
        a1 += xv * __uint_as_float(q.x & 0xFFFF0000u);
        a2 += xv * __uint_as_float(q.y << 16);
        a3 += xv * __uint_as_float(q.y & 0xFFFF0000u);
    }
    // reduce g-pairs within each wave (g0+g1 in wave0, g2+g3 in wave1)
    a0 += __shfl_xor(a0, 32);
    a1 += __shfl_xor(a1, 32);
    a2 += __shfl_xor(a2, 32);
    a3 += __shfl_xor(a3, 32);
    __shared__ float red[US];
    int w = t >> 6, l = t & 63;
    if (w == 1 && l < 32) {
        red[l * 4 + 0] = a0; red[l * 4 + 1] = a1;
        red[l * 4 + 2] = a2; red[l * 4 + 3] = a3;
    }
    __syncthreads();
    if (w == 0 && l < 32) {
        float4 o = make_float4(a0 + red[l * 4 + 0], a1 + red[l * 4 + 1],
                               a2 + red[l * 4 + 2], a3 + red[l * 4 + 3]);
        *reinterpret_cast<float4*>(&out[(size_t)n * US + l * 4]) = o;
    }
}

// --- Fallback tier 1: sorted edge-id list (global hist + 3-level scan) ---
constexpr int SCAN_BLOCK = 256;
constexpr int SCAN_ITEMS = 8;
constexpr int SCAN_CHUNK = SCAN_BLOCK * SCAN_ITEMS;

__global__ void __launch_bounds__(256) hist_kernel(
        const int* __restrict__ dst, int* __restrict__ counts, int E) {
    int e = blockIdx.x * blockDim.x + threadIdx.x;
    if (e < E) atomicAdd(&counts[dst[e]], 1);
}
__global__ void __launch_bounds__(SCAN_BLOCK) block_sum_kernel(
        const int* __restrict__ counts, int* __restrict__ bsums, int N) {
    __shared__ int sdata[SCAN_BLOCK];
    int base = blockIdx.x * SCAN_CHUNK;
    int sum = 0;
    for (int j = 0; j < SCAN_ITEMS; ++j) {
        int idx = base + j * SCAN_BLOCK + threadIdx.x;
        if (idx < N) sum += counts[idx];
    }
    sdata[threadIdx.x] = sum;
    __syncthreads();
    for (int off = SCAN_BLOCK / 2; off > 0; off >>= 1) {
        if (threadIdx.x < off) sdata[threadIdx.x] += sdata[threadIdx.x + off];
        __syncthreads();
    }
    if (threadIdx.x == 0) bsums[blockIdx.x] = sdata[0];
}
__global__ void scan_bsums_kernel(int* __restrict__ bsums, int nb) {
    if (threadIdx.x == 0 && blockIdx.x == 0) {
        int acc = 0;
        for (int i = 0; i < nb; ++i) { int v = bsums[i]; bsums[i] = acc; acc += v; }
    }
}
__global__ void __launch_bounds__(SCAN_BLOCK) scan_final_kernel(
        const int* __restrict__ counts, const int* __restrict__ bsums,
        int* __restrict__ offsets, int* __restrict__ cursors, int N, int E) {
    __shared__ int sdata[SCAN_BLOCK];
    int base = blockIdx.x * SCAN_CHUNK + threadIdx.x * SCAN_ITEMS;
    int local[SCAN_ITEMS];
    int tsum = 0;
    for (int j = 0; j < SCAN_ITEMS; ++j) {
        int idx = base + j;
        int v = (idx < N) ? counts[idx] : 0;
        local[j] = tsum;
        tsum += v;
    }
    sdata[threadIdx.x] = tsum;
    __syncthreads();
    for (int off = 1; off < SCAN_BLOCK; off <<= 1) {
        int v = (threadIdx.x >= off) ? sdata[threadIdx.x - off] : 0;
        __syncthreads();
        sdata[threadIdx.x] += v;
        __syncthreads();
    }
    int excl = sdata[threadIdx.x] - tsum + bsums[blockIdx.x];
    for (int j = 0; j < SCAN_ITEMS; ++j) {
        int idx = base + j;
        if (idx < N) { int o = excl + local[j]; offsets[idx] = o; cursors[idx] = o; }
    }
    if (blockIdx.x == 0 && threadIdx.x == 0) offsets[N] = E;
}
__global__ void __launch_bounds__(256) scatter_ids_kernel(
        const int* __restrict__ dst, int* __restrict__ cursors,
        int* __restrict__ eids, int E) {
    int e = blockIdx.x * blockDim.x + threadIdx.x;
    if (e < E) { int pos = atomicAdd(&cursors[dst[e]], 1); eids[pos] = e; }
}
__global__ void __launch_bounds__(US) accum_ids_kernel(
        const float* __restrict__ x, const float* __restrict__ sh,
        const int* __restrict__ src, const int* __restrict__ offsets,
        const int* __restrict__ eids, float* __restrict__ out) {
    int n = blockIdx.x;
    int t = threadIdx.x;
    int u = t >> 2, s = t & 3;
    int beg = offsets[n], end = offsets[n + 1];
    float acc = 0.f;
    for (int i = beg; i < end; ++i) {
        int e = eids[i];
        acc += x[src[e] * U_DIM + u] * sh[e * S_DIM + s];
    }
    out[(size_t)n * US + t] = acc;
}
__global__ void __launch_bounds__(US) atomic_kernel(
        const float* __restrict__ x, const float* __restrict__ sh,
        const int* __restrict__ src, const int* __restrict__ dst,
        float* __restrict__ out, int E) {
    int e = blockIdx.x;
    int t = threadIdx.x;
    float v = x[src[e] * U_DIM + (t >> 2)] * sh[e * S_DIM + (t & 3)];
    atomicAdd(&out[(size_t)dst[e] * US + t], v);
}

extern "C" void kernel_launch(void* const* d_in, const int* in_sizes, int n_in,
                              void* d_out, int out_size, void* d_ws, size_t ws_size,
                              hipStream_t stream) {
    const float* x  = (const float*)d_in[0];
    const float* sh = (const float*)d_in[1];
    const int* src  = (const int*)d_in[2];
    const int* dst  = (const int*)d_in[3];
    float* out = (float*)d_out;

    const int E = in_sizes[2];
    const int N = in_sizes[0] / U_DIM;
    const int K = (N + NPBK - 1) >> LOG_NPBK;
    const int EPB = (E + NBLK - 1) / NBLK;
    const int egrid = (E + 255) / 256;
    const int nb = (N + SCAN_CHUNK - 1) / SCAN_CHUNK;
    const int xn4 = in_sizes[0] / 4;

    // Primary: pay8 uint2[E] | spill_pay uint2[SPILL_E] | packed int[E] |
    //          spill_pk int[SPILL_E] | offsets[N+1] | ccount[K] | cbase[K+1] |
    //          cnt[K*NBLK] | base_tab[K*NBLK] | spill_cursor[1] | xb ushort[N*32]
    size_t need_main = (size_t)E * 8 + (size_t)SPILL_E * 8 + (size_t)E * 4 +
                       (size_t)SPILL_E * 4 + (size_t)(N + 1) * 4 +
                       (size_t)(2 * K + 2) * 4 + (size_t)(2 * K * NBLK) * 4 +
                       (size_t)in_sizes[0] * 2;
    size_t need_ids = (size_t)E * 4 + (size_t)(3 * N + 1 + nb) * 4;

    if (K <= MAXK && (in_sizes[0] % 4 == 0) && ws_size >= need_main) {
        uint2* pay8      = (uint2*)d_ws;
        uint2* spill_pay = pay8 + E;
        int* packed      = (int*)(spill_pay + SPILL_E);
        int* spill_pk    = packed + E;
        int* offsets     = spill_pk + SPILL_E;
        int* ccount      = offsets + N + 1;
        int* cbase       = ccount + K;
        int* cnt         = cbase + K + 1;
        int* base_tab    = cnt + K * NBLK;
        int* spill_cur   = base_tab + K * NBLK;
        unsigned short* xb = (unsigned short*)(spill_cur + 1);

        hipMemsetAsync(ccount, 0, sizeof(int) * (size_t)K, stream);
        xcvt_kernel<<<(xn4 + 255) / 256, 256, 0, stream>>>(
            (const float4*)x, (ushort4*)xb, xn4);
        coarse_hist_kernel<<<NBLK, 1024, 0, stream>>>(dst, ccount, cnt, E, K, EPB);
        coarse_scan_kernel<<<1, 1024, 0, stream>>>(ccount, cbase, offsets,
                                                   spill_cur, K, N, E);
        chunk_base_kernel<<<K, NBLK, 0, stream>>>(cnt, cbase, base_tab);
        coarse_scatter_kernel<<<NBLK, 1024, 0, stream>>>(dst, src, (const float4*)sh,
                                                         base_tab, pay8, packed,
                                                         E, K, EPB);
        fine_sort_kernel<<<K, 512, 0, stream>>>(cbase, offsets, pay8, packed,
                                                spill_pay, spill_pk, spill_cur, N);
        accum_kernel<<<N, US, 0, stream>>>(xb, pay8, packed, offsets, out);
    } else if (ws_size >= need_ids) {
        int* eids    = (int*)d_ws;
        int* counts  = eids + E;
        int* offsets = counts + N;
        int* cursors = offsets + N + 1;
        int* bsums   = cursors + N;

        hipMemsetAsync(counts, 0, sizeof(int) * (size_t)N, stream);
        hist_kernel<<<egrid, 256, 0, stream>>>(dst, counts, E);
        block_sum_kernel<<<nb, SCAN_BLOCK, 0, stream>>>(counts, bsums, N);
        scan_bsums_kernel<<<1, 64, 0, stream>>>(bsums, nb);
        scan_final_kernel<<<nb, SCAN_BLOCK, 0, stream>>>(counts, bsums, offsets, cursors, N, E);
        scatter_ids_kernel<<<egrid, 256, 0, stream>>>(dst, cursors, eids, E);
        accum_ids_kernel<<<N, US, 0, stream>>>(x, sh, src, offsets, eids, out);
    } else {
        hipMemsetAsync(out, 0, sizeof(float) * (size_t)out_size, stream);
        atomic_kernel<<<E, US, 0, stream>>>(x, sh, src, dst, out, E);
    }
}